// Round 9
// baseline (1483.887 us; speedup 1.0000x reference)
//
#include <hip/hip_runtime.h>

// AdEx Euler integration, fp32 port of the jax/numpy reference.
// T=40000 sequential steps; N=1024 neurons -> 16 producer waves on 16 CUs.
//
// MODEL (R1-R22): lone in-order producer wave; wall = issue + stalls.
// Ledger at R21/R22: 10.0 slots/step = ~61 cyc issue (VALU 5.6, VMEM ~13,
// DS ~8) vs 71 cyc measured -> ~10 cyc/step residual = v_exp_f32 latency
// bubble (only pk1+pk2 ~11 cyc of cover between exp and its consumer).
// Slot ledger EXHAUSTED (R22 pk_add fusion = exact wash, insert-mov).
// Proven-out: C-level reg prefetch arrays get SUNK (R15); AD via LDS
// serializes on lgkmcnt (R16); per-step uniform branch = +18cyc/step
// hazard (R18, banned). Ladder: R17 1354; R19 1340; R20 1298; R21/22 1185.
//
// R23 (this): fill the exp shadow; zero fp-op changes (R21 DAG restored).
//   - AD loads 1-per-pair, issued inside STEP A between exp and pk1
//     (was: 16-burst before body). VMEM issue (~13cyc) overlaps the
//     bubble. Wait becomes vmcnt(0) per buffer (the burst/vmcnt(16)
//     accounting no longer applies); newest outstanding load is ~140+cyc
//     old and AD is L2-resident (~200cyc) -> near-free.
//   - ds_write2st64 moved inside STEP B between exp and pk1 (VWa/VWb
//     final there; register reads at issue; SSA protects later redef).
//   - flag pre-read hoisted between the two PRODUCEs (stale-conservative).
// Predict kernel ~1000-1100us; absmax EXACTLY 4.882812e-04; conflicts 0.
// If wash (>=1160): bubble theory dead -> issue floor; declare ceiling.

typedef float v2f __attribute__((ext_vector_type(2)));
typedef float v4f __attribute__((ext_vector_type(4)));

// ---------------------------------------------------------------------------
// Prep: AD[k] = {Ar2_k, delta} for k in [0, T+32). Bit-identical constant
// folding to the producer's original in-loop computation (same f64
// expressions, rounded once to f32; same fmaf on the same I value).
// ---------------------------------------------------------------------------
__global__ void __launch_bounds__(256) adex_prep_kernel(
    const float* __restrict__ I_ext,
    const float* __restrict__ p_V_rest,
    const float* __restrict__ p_R,
    const float* __restrict__ p_tau,
    const float* __restrict__ p_tau_w,
    const float* __restrict__ p_a,
    float2* __restrict__ AD, int T)
{
#pragma clang fp contract(off)
    int k = blockIdx.x * 256 + threadIdx.x;
    if (k >= T + 32) return;

    const float V_rest = *p_V_rest;
    const float R      = *p_R;
    const float tau    = *p_tau;
    const float tau_w  = *p_tau_w;
    const float a      = *p_a;
    const float dt     = 5e-5f;

    const double dcv = (double)dt / (double)tau;
    const double dcw = (double)dt / (double)tau_w;

    const float cRI   = (float)(dcv * (double)R);
    const float cVr2  = (float)(dcv * (double)V_rest);
    const float delta = (float)(-(double)a * dcw * (double)V_rest);

    int ki = (k <= T + 4) ? k : (T + 4);      // tail entries never consumed
    AD[k] = make_float2(fmaf(cRI, I_ext[ki], cVr2), delta);
}

// ---------------------------------------------------------------------------
// Main producer/consumer kernel.
// ---------------------------------------------------------------------------
__global__ void __launch_bounds__(128, 1) adex_pc_kernel(
    const float* __restrict__ V0,
    const float* __restrict__ w0,
    const float* __restrict__ p_V_reset,
    const float* __restrict__ p_V_T,
    const float* __restrict__ p_V_thres,
    const float* __restrict__ p_delta_T,
    const float* __restrict__ p_R,
    const float* __restrict__ p_tau,
    const float* __restrict__ p_tau_w,
    const float* __restrict__ p_a,
    const float* __restrict__ p_b,
    const float* __restrict__ ADf,       // workspace: {Ar2,delta} pairs
    float* __restrict__ out,
    int T, int N)
{
#pragma clang fp contract(off)
    // Ring of 4 buffers x 32 steps x 64 lanes x float2 = 64 KiB.
    // [buf][step][lane]: lane stride 8B (conflict-free, measured 0);
    // step stride 512B = the ds_*st64 b64 unit.
    __shared__ v2f stage[4][32][64];
    __shared__ int flags[2];             // [0]=produced bufs, [1]=consumed

    const int tid   = threadIdx.x;
    const int l     = tid & 63;
    const int wave  = tid >> 6;
    const int nbase = blockIdx.x * 64;   // N % 64 == 0

    volatile int* vflags = (volatile int*)flags;
    if (tid < 2) flags[tid] = 0;
    __syncthreads();                     // once, at kernel start only

    const int NB = T >> 5;               // 32-step buffers (T % 64 == 0 -> NB even)

    if (wave == 0) {
        // ---------------- producer: the serial recurrence ----------------
        __builtin_amdgcn_s_setprio(3);   // favor the serial-chain wave

        const float V_reset = *p_V_reset;
        const float V_T     = *p_V_T;
        const float V_thres = *p_V_thres;
        const float delta_T = *p_delta_T;
        const float R       = *p_R;
        const float tau     = *p_tau;
        const float tau_w   = *p_tau_w;
        const float a       = *p_a;
        const float b       = *p_b;
        const float dt      = 5e-5f;

        // Constants folded in f64, rounded once to f32 (bit-neutral class).
        const double dT  = (double)delta_T;
        const double dcv = (double)dt / (double)tau;
        const double dcw = (double)dt / (double)tau_w;
        const double l2e = 1.4426950408889634;

        const float c_exp = (float)(l2e / dT);
        const float c2    = (float)(log2(dT * dcv) - (double)V_T * (l2e / dT));
        const float alpha = (float)(1.0 - dcv);
        const float ncRv  = (float)(-dcv * (double)R);
        const float beta  = (float)(1.0 - dcw);
        const float gamma = (float)((double)a * dcw);

        // Packed coefficient pairs for v_pk_fma_f32.
        v2f cAG; cAG.x = alpha; cAG.y = gamma;
        v2f cNB; cNB.x = ncRv;  cNB.y = beta;

        // Ping-pong packed state {V, w}. VWa = state entering the step pair.
        v2f VWa, VWb;
        VWa.x = V0[nbase + l];
        VWa.y = w0[nbase + l];

        // AD double-buffer register sets (16 quads = 64 VGPR each), defined
        // only by volatile asm loads -> unsinkable, guaranteed resident.
        v4f A4[16], B4[16];
        const unsigned long long adbase = (unsigned long long)ADf;

        // Prologue burst for buffer 0 (drained by the first PRODUCE's
        // vmcnt(0)).
#define LDSET(ARR, VOFF)                                                  \
        {                                                                 \
            unsigned _vo = (VOFF);                                        \
            _Pragma("unroll")                                             \
            for (int j = 0; j < 16; ++j)                                  \
                asm volatile("global_load_dwordx4 %0, %1, %2 offset:%3"   \
                             : "=v"(ARR[j])                               \
                             : "v"(_vo), "s"(adbase), "n"(j * 16));       \
        }

        // One step S -> D with a FILLER placed between exp and pk1 to
        // occupy the v_exp_f32 latency shadow. All fp ops value-identical
        // to the verified R14/R21 math:
        //   P1.lo = fma(alpha,S.V,Ar2)   P1.hi = fma(gamma,S.V,delta)
        //   D.lo  = fma(ncRv,S.w,P1.lo)  D.hi  = fma(beta,S.w,P1.hi)
        //   D.V  += 2^fma(S.V,c_exp,c2); unconditional spike selects
        // (NO per-step branch -- R18 lesson).
#define STEPF(S, D, ADW, ...)                                             \
        {                                                                 \
            float u  = fmaf((S).x, c_exp, c2);                            \
            bool  sp = (S).x > V_thres;                                   \
            float ex;                                                     \
            asm("v_exp_f32 %0, %1" : "=v"(ex) : "v"(u));                  \
            __VA_ARGS__;                                                  \
            v2f P1;                                                       \
            asm("v_pk_fma_f32 %0, %1, %2, %3 op_sel:[0,0,0] op_sel_hi:[1,0,1]" \
                : "=v"(P1) : "v"(cAG), "v"(S), "v"(ADW));                 \
            asm("v_pk_fma_f32 %0, %1, %2, %3 op_sel:[0,1,0] op_sel_hi:[1,1,1]" \
                : "=v"(D) : "v"(cNB), "v"(S), "v"(P1));                   \
            (D).x += ex;                                                  \
            float wns = (D).y + b;                                        \
            (D).x = sp ? V_reset : (D).x;                                 \
            (D).y = sp ? wns : (D).y;                                     \
        }

        // One 32-step buffer from register set CUR, interleave-loading NXT
        // (1 dwordx4 per pair, in STEP A's exp shadow; ds_write2st64 in
        // STEP B's exp shadow). vmcnt(0) at top: every outstanding load is
        // >=140cyc old and AD is L2-resident -> near-free drain; makes CUR
        // architecturally resident. sched_barrier per rule #18. NO LGKM0
        // before the flag write (DS pipe in-order per wave, R19-proven).
#define PRODUCE(CUR, NXT, NVOFF)                                          \
        {                                                                 \
            asm volatile("s_waitcnt vmcnt(0)");                           \
            __builtin_amdgcn_sched_barrier(0);                            \
            unsigned lds_a = (unsigned)(unsigned long long)               \
                (__attribute__((address_space(3))) void*)&stage[pi & 3][0][l]; \
            unsigned _nvo = (NVOFF);                                      \
            _Pragma("unroll")                                             \
            for (int s = 0; s < 16; ++s) {                                \
                v4f q = CUR[s];                                           \
                v2f ad0 = __builtin_shufflevector(q, q, 0, 1);            \
                v2f ad1 = __builtin_shufflevector(q, q, 2, 3);            \
                STEPF(VWa, VWb, ad0,                                      \
                    asm volatile("global_load_dwordx4 %0, %1, %2 offset:%3" \
                                 : "=v"(NXT[s])                           \
                                 : "v"(_nvo), "s"(adbase), "n"(s * 16))); \
                STEPF(VWb, VWa, ad1,                                      \
                    asm volatile("ds_write2st64_b64 %0, %1, %2 offset0:%3 offset1:%4" \
                                 :: "v"(lds_a), "v"(VWa), "v"(VWb),       \
                                    "n"(2 * s), "n"(2 * s + 1)));         \
            }                                                             \
            asm volatile("" ::: "memory");                                \
            ++pi;                                                         \
            vflags[0] = pi;                                               \
        }

        // Prologue: buffer 0 into set A (burst; drained by first vmcnt(0)).
        LDSET(A4, 0u);

        int pi = 0;
        unsigned voff = 0;
        int fc = 0;                      // stale-conservative consumed-flag
        while (pi < NB) {
            // Back-pressure (ring 4 deep): producing pi and pi+1 needs
            // consumed >= pi-2. fc was pre-read one buffer ago (can only
            // be smaller than current -> conservative); fresh re-read in
            // the poll loop only if the consumer looks behind.
            if (fc < pi - 2) {
                while (vflags[1] < pi - 2) __builtin_amdgcn_s_sleep(2);
            }
            asm volatile("" ::: "memory");

            PRODUCE(A4, B4, voff + 256);   // produce pi,   load pi+1
            fc = vflags[1];                // pre-read for next iteration
            PRODUCE(B4, A4, voff + 512);   // produce pi+1, load pi+2
                                           // (last issue reads the
                                           //  (T+32)-entry AD tail)
            voff += 512;
        }
#undef PRODUCE
#undef STEPF
#undef LDSET
    } else {
        // ---------------- consumer: drain LDS -> global ----------------
        float* __restrict__ outw = out + (size_t)T * N;
        unsigned idx = (unsigned)(nbase + l);      // += N per step

        for (int ci = 0; ci < NB; ++ci) {
            while (vflags[0] < ci + 1) __builtin_amdgcn_s_sleep(2);
            asm volatile("" ::: "memory");
            const v2f* cb = &stage[ci & 3][0][l];
#pragma unroll
            for (int s = 0; s < 32; ++s) {
                v2f q = cb[s * 64];
                out[idx]  = q.x;
                outw[idx] = q.y;
                idx += (unsigned)N;
            }
            // LDS reads retired (store data deps forced waits); slot free.
            asm volatile("" ::: "memory");
            vflags[1] = ci + 1;
        }
    }
}

// Fallback: R11-style single-wave kernel for shapes that don't meet the
// producer/consumer preconditions (N%64, T%64, workspace size).
__global__ void __launch_bounds__(64, 1) adex_fallback_kernel(
    const float* __restrict__ I_ext,
    const float* __restrict__ V0,
    const float* __restrict__ w0,
    const float* __restrict__ p_V_rest,
    const float* __restrict__ p_V_reset,
    const float* __restrict__ p_V_T,
    const float* __restrict__ p_V_thres,
    const float* __restrict__ p_delta_T,
    const float* __restrict__ p_R,
    const float* __restrict__ p_tau,
    const float* __restrict__ p_tau_w,
    const float* __restrict__ p_a,
    const float* __restrict__ p_b,
    float* __restrict__ out,
    int T, int N)
{
#pragma clang fp contract(off)
    const int l     = threadIdx.x;
    const int nbase = blockIdx.x * 64;
    int n = nbase + l;
    if (n >= N) n = N - 1;

    const float V_rest  = *p_V_rest;
    const float V_reset = *p_V_reset;
    const float V_T     = *p_V_T;
    const float V_thres = *p_V_thres;
    const float delta_T = *p_delta_T;
    const float R       = *p_R;
    const float tau     = *p_tau;
    const float tau_w   = *p_tau_w;
    const float a       = *p_a;
    const float b       = *p_b;
    const float dt      = 5e-5f;

    const double dT  = (double)delta_T;
    const double dcv = (double)dt / (double)tau;
    const double dcw = (double)dt / (double)tau_w;
    const double l2e = 1.4426950408889634;

    const float c_exp = (float)(l2e / dT);
    const float c2    = (float)(log2(dT * dcv) - (double)V_T * (l2e / dT));
    const float alpha = (float)(1.0 - dcv);
    const float ncRv  = (float)(-dcv * (double)R);
    const float beta  = (float)(1.0 - dcw);
    const float gamma = (float)((double)a * dcw);
    const float delta = (float)(-(double)a * dcw * (double)V_rest);
    const float cRI   = (float)(dcv * (double)R);
    const float cVr2  = (float)(dcv * (double)V_rest);

    float V = V0[n];
    float w = w0[n];

    float* outVb = out + nbase;
    float* outWb = out + (size_t)T * N + nbase;

#define ADEX_STEP(Ar2_k)                                            \
    {                                                               \
        outVb[l] = V;                                               \
        outWb[l] = w;                                               \
        outVb += N;                                                 \
        outWb += N;                                                 \
        float u3 = fmaf(V, c_exp, c2);                              \
        float ex3;                                                  \
        asm("v_exp_f32 %0, %1" : "=v"(ex3) : "v"(u3));              \
        float m1  = fmaf(alpha, V, (Ar2_k));                        \
        float m2  = fmaf(ncRv, w, m1);                              \
        float Vn  = m2 + ex3;                                       \
        float t2  = fmaf(gamma, V, delta);                          \
        float wn  = fmaf(beta, w, t2);                              \
        bool  spike = V > V_thres;                                  \
        float wns = wn + b;                                         \
        Vn = spike ? V_reset : Vn;                                  \
        wn = spike ? wns : wn;                                      \
        V = Vn;                                                     \
        w = wn;                                                     \
    }

    float A[16], B[16];
#pragma unroll
    for (int j = 0; j < 16; ++j) A[j] = fmaf(cRI, I_ext[j], cVr2);

    for (int kb = 0; kb < T; kb += 32) {
#pragma unroll
        for (int j = 0; j < 16; ++j)
            B[j] = fmaf(cRI, I_ext[kb + 16 + j], cVr2);
#pragma unroll
        for (int j = 0; j < 16; ++j) ADEX_STEP(A[j]);
        {
            int pb = kb + 32;
            if (pb > T - 11) pb = T - 11;
#pragma unroll
            for (int j = 0; j < 16; ++j)
                A[j] = fmaf(cRI, I_ext[pb + j], cVr2);
        }
#pragma unroll
        for (int j = 0; j < 16; ++j) ADEX_STEP(B[j]);
    }
#undef ADEX_STEP
}

extern "C" void kernel_launch(void* const* d_in, const int* in_sizes, int n_in,
                              void* d_out, int out_size, void* d_ws, size_t ws_size,
                              hipStream_t stream) {
    const float* I_ext = (const float*)d_in[0];
    const float* V0    = (const float*)d_in[1];
    const float* w0    = (const float*)d_in[2];

    const int N = in_sizes[1];          // 1024 (multiple of 64)
    const int T = out_size / (2 * N);   // 40000 (multiple of 64)

    const size_t ws_need = (size_t)(T + 32) * sizeof(float2);

    if ((N % 64 == 0) && (T % 64 == 0) && d_ws != nullptr && ws_size >= ws_need) {
        adex_prep_kernel<<<(T + 32 + 255) / 256, 256, 0, stream>>>(
            I_ext,
            (const float*)d_in[3],      // V_rest
            (const float*)d_in[8],      // R
            (const float*)d_in[9],      // tau
            (const float*)d_in[10],     // tau_w
            (const float*)d_in[11],     // a
            (float2*)d_ws, T);
        adex_pc_kernel<<<N / 64, 128, 0, stream>>>(
            V0, w0,
            (const float*)d_in[4],      // V_reset
            (const float*)d_in[5],      // V_T
            (const float*)d_in[6],      // V_thres
            (const float*)d_in[7],      // delta_T
            (const float*)d_in[8],      // R
            (const float*)d_in[9],      // tau
            (const float*)d_in[10],     // tau_w
            (const float*)d_in[11],     // a
            (const float*)d_in[12],     // b
            (const float*)d_ws,
            (float*)d_out, T, N);
    } else {
        adex_fallback_kernel<<<(N + 63) / 64, 64, 0, stream>>>(
            I_ext, V0, w0,
            (const float*)d_in[3], (const float*)d_in[4], (const float*)d_in[5],
            (const float*)d_in[6], (const float*)d_in[7], (const float*)d_in[8],
            (const float*)d_in[9], (const float*)d_in[10], (const float*)d_in[11],
            (const float*)d_in[12], (float*)d_out, T, N);
    }
}

// Round 10
// 1439.489 us; speedup vs baseline: 1.0308x; 1.0308x over previous
//
#include <hip/hip_runtime.h>

// AdEx Euler integration, fp32 port of the jax/numpy reference.
// T=40000 sequential steps; N=1024 neurons -> 16 producer waves on 16 CUs.
//
// MODEL (R1-R23): lone in-order producer wave; wall = dependency-chained
// issue of ~10 slots/step (9 VALU x ~5-6cyc + 0.5 DS + 0.5 VMEM) ~= 64-70
// cyc vs 71 measured -> within ~10% of honest floor. R23 falsified the
// "big exp bubble" theory: interleaving VMEM into the exp shadow bought 0
// and its vmcnt(0)-per-buffer drain cost +2cyc/step (1185 -> 1208).
// Proven-out: C-level reg prefetch arrays get SUNK (R15); AD via LDS
// serializes on lgkmcnt (R16); per-step uniform branch = +18cyc/step
// hazard (R18, banned); pk_add epilogue fusion = wash, insert-mov (R22).
// Ladder: R17 1354; R19 1340; R20 1298; R21/R22 1185(6).
//
// R24 (this): revert to R21 exactly (burst LDSET + vmcnt(16), proven
// 1186us) and isolate the ONE untested half of R23: ds_write2st64 moved
// into step B's exp shadow (in R21 it sat serially between the step pair,
// ~8cyc on the critical path; now its issue overlaps exp latency).
// Values identical -- VWa/VWb final at that point; later VWa redef is
// SSA-safe (placement proven bit-exact in R23). Zero fp changes.
// Predict ~1120-1186us; absmax EXACTLY 4.882812e-04; conflicts 0.
// If >=1180: ledger + stall list exhausted -> declare structural ceiling.

typedef float v2f __attribute__((ext_vector_type(2)));
typedef float v4f __attribute__((ext_vector_type(4)));

// ---------------------------------------------------------------------------
// Prep: AD[k] = {Ar2_k, delta} for k in [0, T+32). Bit-identical constant
// folding to the producer's original in-loop computation (same f64
// expressions, rounded once to f32; same fmaf on the same I value).
// ---------------------------------------------------------------------------
__global__ void __launch_bounds__(256) adex_prep_kernel(
    const float* __restrict__ I_ext,
    const float* __restrict__ p_V_rest,
    const float* __restrict__ p_R,
    const float* __restrict__ p_tau,
    const float* __restrict__ p_tau_w,
    const float* __restrict__ p_a,
    float2* __restrict__ AD, int T)
{
#pragma clang fp contract(off)
    int k = blockIdx.x * 256 + threadIdx.x;
    if (k >= T + 32) return;

    const float V_rest = *p_V_rest;
    const float R      = *p_R;
    const float tau    = *p_tau;
    const float tau_w  = *p_tau_w;
    const float a      = *p_a;
    const float dt     = 5e-5f;

    const double dcv = (double)dt / (double)tau;
    const double dcw = (double)dt / (double)tau_w;

    const float cRI   = (float)(dcv * (double)R);
    const float cVr2  = (float)(dcv * (double)V_rest);
    const float delta = (float)(-(double)a * dcw * (double)V_rest);

    int ki = (k <= T + 4) ? k : (T + 4);      // tail entries never consumed
    AD[k] = make_float2(fmaf(cRI, I_ext[ki], cVr2), delta);
}

// ---------------------------------------------------------------------------
// Main producer/consumer kernel.
// ---------------------------------------------------------------------------
__global__ void __launch_bounds__(128, 1) adex_pc_kernel(
    const float* __restrict__ V0,
    const float* __restrict__ w0,
    const float* __restrict__ p_V_reset,
    const float* __restrict__ p_V_T,
    const float* __restrict__ p_V_thres,
    const float* __restrict__ p_delta_T,
    const float* __restrict__ p_R,
    const float* __restrict__ p_tau,
    const float* __restrict__ p_tau_w,
    const float* __restrict__ p_a,
    const float* __restrict__ p_b,
    const float* __restrict__ ADf,       // workspace: {Ar2,delta} pairs
    float* __restrict__ out,
    int T, int N)
{
#pragma clang fp contract(off)
    // Ring of 4 buffers x 32 steps x 64 lanes x float2 = 64 KiB.
    // [buf][step][lane]: lane stride 8B (conflict-free, measured 0);
    // step stride 512B = the ds_*st64 b64 unit.
    __shared__ v2f stage[4][32][64];
    __shared__ int flags[2];             // [0]=produced bufs, [1]=consumed

    const int tid   = threadIdx.x;
    const int l     = tid & 63;
    const int wave  = tid >> 6;
    const int nbase = blockIdx.x * 64;   // N % 64 == 0

    volatile int* vflags = (volatile int*)flags;
    if (tid < 2) flags[tid] = 0;
    __syncthreads();                     // once, at kernel start only

    const int NB = T >> 5;               // 32-step buffers (T % 64 == 0 -> NB even)

    if (wave == 0) {
        // ---------------- producer: the serial recurrence ----------------
        __builtin_amdgcn_s_setprio(3);   // favor the serial-chain wave

        const float V_reset = *p_V_reset;
        const float V_T     = *p_V_T;
        const float V_thres = *p_V_thres;
        const float delta_T = *p_delta_T;
        const float R       = *p_R;
        const float tau     = *p_tau;
        const float tau_w   = *p_tau_w;
        const float a       = *p_a;
        const float b       = *p_b;
        const float dt      = 5e-5f;

        // Constants folded in f64, rounded once to f32 (bit-neutral class).
        const double dT  = (double)delta_T;
        const double dcv = (double)dt / (double)tau;
        const double dcw = (double)dt / (double)tau_w;
        const double l2e = 1.4426950408889634;

        const float c_exp = (float)(l2e / dT);
        const float c2    = (float)(log2(dT * dcv) - (double)V_T * (l2e / dT));
        const float alpha = (float)(1.0 - dcv);
        const float ncRv  = (float)(-dcv * (double)R);
        const float beta  = (float)(1.0 - dcw);
        const float gamma = (float)((double)a * dcw);

        // Packed coefficient pairs for v_pk_fma_f32.
        v2f cAG; cAG.x = alpha; cAG.y = gamma;
        v2f cNB; cNB.x = ncRv;  cNB.y = beta;

        // Ping-pong packed state {V, w}. VWa = state entering the step pair.
        v2f VWa, VWb;
        VWa.x = V0[nbase + l];
        VWa.y = w0[nbase + l];

        // AD double-buffer register sets (16 quads = 64 VGPR each), defined
        // only by volatile asm loads -> unsinkable, guaranteed resident.
        v4f A4[16], B4[16];
        const unsigned long long adbase = (unsigned long long)ADf;

#define LDSET(ARR, VOFF)                                                  \
        {                                                                 \
            unsigned _vo = (VOFF);                                        \
            _Pragma("unroll")                                             \
            for (int j = 0; j < 16; ++j)                                  \
                asm volatile("global_load_dwordx4 %0, %1, %2 offset:%3"   \
                             : "=v"(ARR[j])                               \
                             : "v"(_vo), "s"(adbase), "n"(j * 16));       \
        }

        // One step S -> D with an optional FILLER placed between exp and
        // pk1 (the exp latency shadow). All fp ops value-identical to the
        // verified R14/R21 math:
        //   P1.lo = fma(alpha,S.V,Ar2)   P1.hi = fma(gamma,S.V,delta)
        //   D.lo  = fma(ncRv,S.w,P1.lo)  D.hi  = fma(beta,S.w,P1.hi)
        //   D.V  += 2^fma(S.V,c_exp,c2); unconditional spike selects
        // (NO per-step branch -- R18 lesson).
#define STEPF(S, D, ADW, ...)                                             \
        {                                                                 \
            float u  = fmaf((S).x, c_exp, c2);                            \
            bool  sp = (S).x > V_thres;                                   \
            float ex;                                                     \
            asm("v_exp_f32 %0, %1" : "=v"(ex) : "v"(u));                  \
            __VA_ARGS__;                                                  \
            v2f P1;                                                       \
            asm("v_pk_fma_f32 %0, %1, %2, %3 op_sel:[0,0,0] op_sel_hi:[1,0,1]" \
                : "=v"(P1) : "v"(cAG), "v"(S), "v"(ADW));                 \
            asm("v_pk_fma_f32 %0, %1, %2, %3 op_sel:[0,1,0] op_sel_hi:[1,1,1]" \
                : "=v"(D) : "v"(cNB), "v"(S), "v"(P1));                   \
            (D).x += ex;                                                  \
            float wns = (D).y + b;                                        \
            (D).x = sp ? V_reset : (D).x;                                 \
            (D).y = sp ? wns : (D).y;                                     \
        }

        // One 32-step buffer from register set ARR (R21 structure: burst
        // prefetch + vmcnt(16); the 16 newest loads = next buffer stay in
        // flight, ARR's older loads are drained -> resident).
        // ONLY delta vs R21: ds_write2st64 issues inside step B's exp
        // shadow instead of serially between the step pair. It reads VWa
        // (pre-state 2s) and VWb (pre-state 2s+1) -- both final there;
        // step B's later redefinition of VWa is SSA-safe (R23-proven
        // bit-exact placement). NO LGKM0 before the flag write (DS pipe
        // in-order per wave, R19-proven). sched_barrier per rule #18.
#define PRODUCE(ARR)                                                      \
        {                                                                 \
            asm volatile("s_waitcnt vmcnt(16)");                          \
            __builtin_amdgcn_sched_barrier(0);                            \
            unsigned lds_a = (unsigned)(unsigned long long)               \
                (__attribute__((address_space(3))) void*)&stage[pi & 3][0][l]; \
            _Pragma("unroll")                                             \
            for (int s = 0; s < 16; ++s) {                                \
                v4f q = ARR[s];                                           \
                v2f ad0 = __builtin_shufflevector(q, q, 0, 1);            \
                v2f ad1 = __builtin_shufflevector(q, q, 2, 3);            \
                STEPF(VWa, VWb, ad0, );                                   \
                STEPF(VWb, VWa, ad1,                                      \
                    asm volatile("ds_write2st64_b64 %0, %1, %2 offset0:%3 offset1:%4" \
                                 :: "v"(lds_a), "v"(VWa), "v"(VWb),       \
                                    "n"(2 * s), "n"(2 * s + 1)));         \
            }                                                             \
            asm volatile("" ::: "memory");                                \
            ++pi;                                                         \
            vflags[0] = pi;                                               \
        }

        // Prologue: buffer 0 into set A.
        LDSET(A4, 0u);

        int pi = 0;
        unsigned voff = 0;
        while (pi < NB) {
            // Back-pressure (ring 4 deep): producing pi and pi+1 needs
            // consumed >= pi-2. Flag pre-read BEFORE the LDSET burst hides
            // the ~120cyc LDS latency; poll loop only if consumer behind.
            int fc = vflags[1];
            voff += 256;
            LDSET(B4, voff);       // buffer pi+1
            if (fc < pi - 2) {
                while (vflags[1] < pi - 2) __builtin_amdgcn_s_sleep(2);
            }
            asm volatile("" ::: "memory");

            PRODUCE(A4);

            voff += 256;
            LDSET(A4, voff);       // buffer pi+2 (last issue reads the
                                   // (T+32)-entry AD tail; never consumed)
            PRODUCE(B4);
        }
#undef PRODUCE
#undef STEPF
#undef LDSET
    } else {
        // ---------------- consumer: drain LDS -> global ----------------
        float* __restrict__ outw = out + (size_t)T * N;
        unsigned idx = (unsigned)(nbase + l);      // += N per step

        for (int ci = 0; ci < NB; ++ci) {
            while (vflags[0] < ci + 1) __builtin_amdgcn_s_sleep(2);
            asm volatile("" ::: "memory");
            const v2f* cb = &stage[ci & 3][0][l];
#pragma unroll
            for (int s = 0; s < 32; ++s) {
                v2f q = cb[s * 64];
                out[idx]  = q.x;
                outw[idx] = q.y;
                idx += (unsigned)N;
            }
            // LDS reads retired (store data deps forced waits); slot free.
            asm volatile("" ::: "memory");
            vflags[1] = ci + 1;
        }
    }
}

// Fallback: R11-style single-wave kernel for shapes that don't meet the
// producer/consumer preconditions (N%64, T%64, workspace size).
__global__ void __launch_bounds__(64, 1) adex_fallback_kernel(
    const float* __restrict__ I_ext,
    const float* __restrict__ V0,
    const float* __restrict__ w0,
    const float* __restrict__ p_V_rest,
    const float* __restrict__ p_V_reset,
    const float* __restrict__ p_V_T,
    const float* __restrict__ p_V_thres,
    const float* __restrict__ p_delta_T,
    const float* __restrict__ p_R,
    const float* __restrict__ p_tau,
    const float* __restrict__ p_tau_w,
    const float* __restrict__ p_a,
    const float* __restrict__ p_b,
    float* __restrict__ out,
    int T, int N)
{
#pragma clang fp contract(off)
    const int l     = threadIdx.x;
    const int nbase = blockIdx.x * 64;
    int n = nbase + l;
    if (n >= N) n = N - 1;

    const float V_rest  = *p_V_rest;
    const float V_reset = *p_V_reset;
    const float V_T     = *p_V_T;
    const float V_thres = *p_V_thres;
    const float delta_T = *p_delta_T;
    const float R       = *p_R;
    const float tau     = *p_tau;
    const float tau_w   = *p_tau_w;
    const float a       = *p_a;
    const float b       = *p_b;
    const float dt      = 5e-5f;

    const double dT  = (double)delta_T;
    const double dcv = (double)dt / (double)tau;
    const double dcw = (double)dt / (double)tau_w;
    const double l2e = 1.4426950408889634;

    const float c_exp = (float)(l2e / dT);
    const float c2    = (float)(log2(dT * dcv) - (double)V_T * (l2e / dT));
    const float alpha = (float)(1.0 - dcv);
    const float ncRv  = (float)(-dcv * (double)R);
    const float beta  = (float)(1.0 - dcw);
    const float gamma = (float)((double)a * dcw);
    const float delta = (float)(-(double)a * dcw * (double)V_rest);
    const float cRI   = (float)(dcv * (double)R);
    const float cVr2  = (float)(dcv * (double)V_rest);

    float V = V0[n];
    float w = w0[n];

    float* outVb = out + nbase;
    float* outWb = out + (size_t)T * N + nbase;

#define ADEX_STEP(Ar2_k)                                            \
    {                                                               \
        outVb[l] = V;                                               \
        outWb[l] = w;                                               \
        outVb += N;                                                 \
        outWb += N;                                                 \
        float u3 = fmaf(V, c_exp, c2);                              \
        float ex3;                                                  \
        asm("v_exp_f32 %0, %1" : "=v"(ex3) : "v"(u3));              \
        float m1  = fmaf(alpha, V, (Ar2_k));                        \
        float m2  = fmaf(ncRv, w, m1);                              \
        float Vn  = m2 + ex3;                                       \
        float t2  = fmaf(gamma, V, delta);                          \
        float wn  = fmaf(beta, w, t2);                              \
        bool  spike = V > V_thres;                                  \
        float wns = wn + b;                                         \
        Vn = spike ? V_reset : Vn;                                  \
        wn = spike ? wns : wn;                                      \
        V = Vn;                                                     \
        w = wn;                                                     \
    }

    float A[16], B[16];
#pragma unroll
    for (int j = 0; j < 16; ++j) A[j] = fmaf(cRI, I_ext[j], cVr2);

    for (int kb = 0; kb < T; kb += 32) {
#pragma unroll
        for (int j = 0; j < 16; ++j)
            B[j] = fmaf(cRI, I_ext[kb + 16 + j], cVr2);
#pragma unroll
        for (int j = 0; j < 16; ++j) ADEX_STEP(A[j]);
        {
            int pb = kb + 32;
            if (pb > T - 11) pb = T - 11;
#pragma unroll
            for (int j = 0; j < 16; ++j)
                A[j] = fmaf(cRI, I_ext[pb + j], cVr2);
        }
#pragma unroll
        for (int j = 0; j < 16; ++j) ADEX_STEP(B[j]);
    }
#undef ADEX_STEP
}

extern "C" void kernel_launch(void* const* d_in, const int* in_sizes, int n_in,
                              void* d_out, int out_size, void* d_ws, size_t ws_size,
                              hipStream_t stream) {
    const float* I_ext = (const float*)d_in[0];
    const float* V0    = (const float*)d_in[1];
    const float* w0    = (const float*)d_in[2];

    const int N = in_sizes[1];          // 1024 (multiple of 64)
    const int T = out_size / (2 * N);   // 40000 (multiple of 64)

    const size_t ws_need = (size_t)(T + 32) * sizeof(float2);

    if ((N % 64 == 0) && (T % 64 == 0) && d_ws != nullptr && ws_size >= ws_need) {
        adex_prep_kernel<<<(T + 32 + 255) / 256, 256, 0, stream>>>(
            I_ext,
            (const float*)d_in[3],      // V_rest
            (const float*)d_in[8],      // R
            (const float*)d_in[9],      // tau
            (const float*)d_in[10],     // tau_w
            (const float*)d_in[11],     // a
            (float2*)d_ws, T);
        adex_pc_kernel<<<N / 64, 128, 0, stream>>>(
            V0, w0,
            (const float*)d_in[4],      // V_reset
            (const float*)d_in[5],      // V_T
            (const float*)d_in[6],      // V_thres
            (const float*)d_in[7],      // delta_T
            (const float*)d_in[8],      // R
            (const float*)d_in[9],      // tau
            (const float*)d_in[10],     // tau_w
            (const float*)d_in[11],     // a
            (const float*)d_in[12],     // b
            (const float*)d_ws,
            (float*)d_out, T, N);
    } else {
        adex_fallback_kernel<<<(N + 63) / 64, 64, 0, stream>>>(
            I_ext, V0, w0,
            (const float*)d_in[3], (const float*)d_in[4], (const float*)d_in[5],
            (const float*)d_in[6], (const float*)d_in[7], (const float*)d_in[8],
            (const float*)d_in[9], (const float*)d_in[10], (const float*)d_in[11],
            (const float*)d_in[12], (float*)d_out, T, N);
    }
}